// Round 14
// baseline (213.627 us; speedup 1.0000x reference)
//
#include <hip/hip_runtime.h>

// FixedActionDecoder: sims = (X/||x||) @ (A/||a||cols); segment-max over
// ACTION_INDEX=[0,0,0,0,1,1,1,1,1,2,3]; argmax; one-hot.
// Row-norm of X is argmax-invariant -> skipped.
//
// r14 = "no staging" decode: each thread streams its own TWO rows directly
// global->registers, chunk by chunk; W broadcast from LDS as d-major quads
// (r9-proven). This DELETES the twice-per-tile barrier'd staging stall that
// capped r9 at ~40 cyc/row (floor ~26):
//  - no wave barriers, no LDS X traffic (2.8 KB LDS/block total);
//  - occupancy now VGPR-bound: ~20 waves/CU (2.5x r9) does the latency
//    hiding that staging pipelines (r5/r6/r10) failed to do;
//  - VMEM instr count unchanged (0.25/row); per-instr coalescing worse
//    (64 scattered 16B reqs) but each thread consumes full 64B sectors
//    over 4 consecutive chunks -> L2-absorbed, HBM traffic ~unchanged.
// Convicted-and-banned: DMA staging (r5/r10), reg staging arrays (r6),
// quarter-phases (r7/r8), fused repair (r11), steal atomics (r12).
// Numerics unchanged: f32 pass + gap<TAU ballot -> f64 repair kernel
// (absmax 0 in every passing round). Fallback if this regresses: r13.

#define NP 11
#define TAU 1e-3f

__device__ __align__(16) float g_W32[704];      // [(d>>2)*44 + p*4 + (d&3)]
__device__ double g_W64[704];                   // [d*11 + p]
__device__ unsigned long long g_bits[1 << 20];  // near-tie flags, 1 bit/row

// Parallel prep (~2us): thread d owns row d of A; column norms via LDS.
__global__ void prep(const float* __restrict__ A) {
    __shared__ double sq[64][NP + 1];  // +1 pad
    __shared__ double sc[NP];
    const int d = threadIdx.x;  // 0..63
    double a[NP];
    #pragma unroll
    for (int p = 0; p < NP; ++p) {
        a[p] = (double)A[d * NP + p];
        sq[d][p] = a[p] * a[p];
    }
    __syncthreads();
    if (d < NP) {
        double ss = 0.0;
        #pragma unroll
        for (int r = 0; r < 64; ++r) ss += sq[r][d];
        sc[d] = 1.0 / fmax(sqrt(ss), 1e-8);
    }
    __syncthreads();
    #pragma unroll
    for (int p = 0; p < NP; ++p) {
        double w = a[p] * sc[p];
        g_W64[d * NP + p] = w;
        g_W32[(d >> 2) * 44 + p * 4 + (d & 3)] = (float)w;  // d-major quad
    }
}

__device__ __forceinline__ void argmax_gap(const float* s, int& idx, float& gap) {
    // Segment max per ACTION_INDEX = [0,0,0,0, 1,1,1,1,1, 2, 3]
    float m0 = fmaxf(fmaxf(s[0], s[1]), fmaxf(s[2], s[3]));
    float m1 = fmaxf(fmaxf(fmaxf(s[4], s[5]), s[6]), fmaxf(s[7], s[8]));
    float m2 = s[9], m3 = s[10];
    idx = 0; float best = m0;
    if (m1 > best) { best = m1; idx = 1; }
    if (m2 > best) { best = m2; idx = 2; }
    if (m3 > best) { best = m3; idx = 3; }
    float second = -3.4e38f;
    if (idx != 0) second = fmaxf(second, m0);
    if (idx != 1) second = fmaxf(second, m1);
    if (idx != 2) second = fmaxf(second, m2);
    if (idx != 3) second = fmaxf(second, m3);
    gap = best - second;
}

__global__ __launch_bounds__(256) void decode(const float* __restrict__ X,
                                              float* __restrict__ out, int B) {
    __shared__ float w_lds[704];  // only LDS use: W quads (2816 B)

    const int tid = threadIdx.x;
    const int lane = tid & 63;
    const int wv = tid >> 6;

    for (int t = tid; t < 176; t += 256)
        reinterpret_cast<float4*>(w_lds)[t] =
            reinterpret_cast<const float4*>(g_W32)[t];
    __syncthreads();  // once; no barriers in the main loop

    const float4* X4 = reinterpret_cast<const float4*>(X);
    const int gwave = blockIdx.x * 4 + wv;
    const int nwaves = gridDim.x * 4;

    #pragma unroll 1
    for (int base = gwave * 128; base < B; base += nwaves * 128) {
        const int r0 = base + lane;
        const int r1 = base + 64 + lane;
        const int cr0 = (r0 < B) ? r0 : (B - 1);  // clamp: dup read, no store
        const int cr1 = (r1 < B) ? r1 : (B - 1);
        const float4* __restrict__ row0 = X4 + (size_t)cr0 * 16;
        const float4* __restrict__ row1 = X4 + (size_t)cr1 * 16;

        float acc0[NP], acc1[NP];
        #pragma unroll
        for (int p = 0; p < NP; ++p) { acc0[p] = 0.0f; acc1[p] = 0.0f; }

        // Stream 16 chunks of 4 d-values; each thread owns its rows.
        // unroll 2: doubles load-use distance without bulk W hoisting (r2).
        #pragma unroll 2
        for (int kk = 0; kk < 16; ++kk) {
            float4 x0 = row0[kk];
            float4 x1 = row1[kk];
            const float* wrow = &w_lds[kk * 44];
            #pragma unroll
            for (int p = 0; p < NP; ++p) {
                float4 wq = *reinterpret_cast<const float4*>(&wrow[p * 4]);
                float t0 = fmaf(x0.x, wq.x, acc0[p]);
                t0 = fmaf(x0.y, wq.y, t0);
                t0 = fmaf(x0.z, wq.z, t0);
                acc0[p] = fmaf(x0.w, wq.w, t0);
                float t1 = fmaf(x1.x, wq.x, acc1[p]);
                t1 = fmaf(x1.y, wq.y, t1);
                t1 = fmaf(x1.z, wq.z, t1);
                acc1[p] = fmaf(x1.w, wq.w, t1);
            }
        }

        int idx0, idx1; float gap0, gap1;
        argmax_gap(acc0, idx0, gap0);
        argmax_gap(acc1, idx1, gap1);

        unsigned long long m0 = __ballot(gap0 < TAU);
        unsigned long long m1 = __ballot(gap1 < TAU);
        if (lane == 0) {
            g_bits[(base >> 6) + 0] = m0;
            g_bits[(base >> 6) + 1] = m1;
        }

        if (r0 < B) {
            float4 o;
            o.x = (idx0 == 0) ? 1.0f : 0.0f;
            o.y = (idx0 == 1) ? 1.0f : 0.0f;
            o.z = (idx0 == 2) ? 1.0f : 0.0f;
            o.w = (idx0 == 3) ? 1.0f : 0.0f;
            reinterpret_cast<float4*>(out)[r0] = o;
        }
        if (r1 < B) {
            float4 o;
            o.x = (idx1 == 0) ? 1.0f : 0.0f;
            o.y = (idx1 == 1) ? 1.0f : 0.0f;
            o.z = (idx1 == 2) ? 1.0f : 0.0f;
            o.w = (idx1 == 3) ? 1.0f : 0.0f;
            reinterpret_cast<float4*>(out)[r1] = o;
        }
    }
}

__global__ __launch_bounds__(256) void repair(const float* __restrict__ X,
                                              float* __restrict__ out, int B) {
    __shared__ double w64[704];  // copy of g_W64
    const int tid = threadIdx.x;
    for (int i = tid; i < 704; i += 256) w64[i] = g_W64[i];
    __syncthreads();

    const int nwords = (B + 63) >> 6;
    for (int t = blockIdx.x * blockDim.x + tid; t < nwords;
         t += gridDim.x * blockDim.x) {
        unsigned long long m = g_bits[t];
        while (m) {
            int b = __builtin_ctzll(m);
            m &= m - 1;
            int row = t * 64 + b;
            if (row >= B) continue;

            double s[NP];
            #pragma unroll
            for (int p = 0; p < NP; ++p) s[p] = 0.0;
            #pragma unroll 1
            for (int d = 0; d < 64; ++d) {
                double x = (double)X[(size_t)row * 64 + d];
                #pragma unroll
                for (int p = 0; p < NP; ++p)
                    s[p] = fma(x, w64[d * NP + p], s[p]);
            }

            double m0 = fmax(fmax(s[0], s[1]), fmax(s[2], s[3]));
            double m1 = fmax(fmax(fmax(s[4], s[5]), s[6]), fmax(s[7], s[8]));
            double m2 = s[9], m3 = s[10];
            int idx = 0; double best = m0;
            if (m1 > best) { best = m1; idx = 1; }
            if (m2 > best) { best = m2; idx = 2; }
            if (m3 > best) { best = m3; idx = 3; }

            float4 o;
            o.x = (idx == 0) ? 1.0f : 0.0f;
            o.y = (idx == 1) ? 1.0f : 0.0f;
            o.z = (idx == 2) ? 1.0f : 0.0f;
            o.w = (idx == 3) ? 1.0f : 0.0f;
            reinterpret_cast<float4*>(out)[row] = o;
        }
    }
}

extern "C" void kernel_launch(void* const* d_in, const int* in_sizes, int n_in,
                              void* d_out, int out_size, void* d_ws, size_t ws_size,
                              hipStream_t stream) {
    const float* X = (const float*)d_in[0];
    const float* A = (const float*)d_in[1];
    float* out = (float*)d_out;
    const int B = in_sizes[0] / 64;

    hipLaunchKernelGGL(prep, dim3(1), dim3(64), 0, stream, A);
    hipLaunchKernelGGL(decode, dim3(1024), dim3(256), 0, stream, X, out, B);
    hipLaunchKernelGGL(repair, dim3(128), dim3(256), 0, stream, X, out, B);
}

// Round 15
// 83.444 us; speedup vs baseline: 2.5601x; 2.5601x over previous
//
#include <hip/hip_runtime.h>

// FixedActionDecoder: sims = (X/||x||) @ (A/||a||cols); segment-max over
// ACTION_INDEX=[0,0,0,0,1,1,1,1,1,2,3]; argmax; one-hot.
// Row-norm of X is argmax-invariant -> skipped.
//
// r15 = r13 (=r9, measured best 77.8/78.7us) + SAME-ITERATION register
// prefetch: the 16 staging float4s for phase p+1 are global-loaded at the
// TOP of phase p's compute section and committed to LDS AFTER it, so the
// ~900-cyc HBM latency hides under ~2600 cyc of FMA work. Differences vs
// every convicted variant:
//  - r6 (spill): values here are def'd and used in the SAME iteration -
//    no loop-carried array, no conditional phi (addresses clamp), named
//    scalars pf0..pf15 only (rule 20).
//  - r10 (1 wave/SIMD): LDS unchanged (single buffer/wave, write-after-read
//    is safe in-order within the wave) -> still 4 blk/CU = 8 waves/CU.
//  - r14 (over-fetch): staging pattern identical to r9 - every request
//    covers a full 128B line.
//  - sched_barrier(0) after each load batch pins it above the compute.
// Everything else byte-identical to r13. Sentinels: WRITE_SIZE>25MB=spill;
// dur>78.7 -> revert to r13 and stop.
// Numerics: f32 pass + gap<TAU ballot -> f64 repair (absmax 0 all rounds).

#define NP 11
#define TAU 1e-3f
#define LROW 36  // LDS row stride (dwords): 32 data + 4 pad (0-conflict, PMC)

__device__ __align__(16) float g_W32[704];      // [(d>>2)*44 + p*4 + (d&3)]
__device__ double g_W64[704];                   // [d*11 + p]
__device__ unsigned long long g_bits[1 << 20];  // near-tie flags, 1 bit/row

__global__ void prep(const float* __restrict__ A) {
    __shared__ double sq[64][NP + 1];
    __shared__ double sc[NP];
    const int d = threadIdx.x;  // 0..63
    double a[NP];
    #pragma unroll
    for (int p = 0; p < NP; ++p) {
        a[p] = (double)A[d * NP + p];
        sq[d][p] = a[p] * a[p];
    }
    __syncthreads();
    if (d < NP) {
        double ss = 0.0;
        #pragma unroll
        for (int r = 0; r < 64; ++r) ss += sq[r][d];
        sc[d] = 1.0 / fmax(sqrt(ss), 1e-8);
    }
    __syncthreads();
    #pragma unroll
    for (int p = 0; p < NP; ++p) {
        double w = a[p] * sc[p];
        g_W64[d * NP + p] = w;
        g_W32[(d >> 2) * 44 + p * 4 + (d & 3)] = (float)w;  // d-major quad
    }
}

__device__ __forceinline__ void argmax_gap(const float* s, int& idx, float& gap) {
    // Segment max per ACTION_INDEX = [0,0,0,0, 1,1,1,1,1, 2, 3]
    float m0 = fmaxf(fmaxf(s[0], s[1]), fmaxf(s[2], s[3]));
    float m1 = fmaxf(fmaxf(fmaxf(s[4], s[5]), s[6]), fmaxf(s[7], s[8]));
    float m2 = s[9], m3 = s[10];
    idx = 0; float best = m0;
    if (m1 > best) { best = m1; idx = 1; }
    if (m2 > best) { best = m2; idx = 2; }
    if (m3 > best) { best = m3; idx = 3; }
    float second = -3.4e38f;
    if (idx != 0) second = fmaxf(second, m0);
    if (idx != 1) second = fmaxf(second, m1);
    if (idx != 2) second = fmaxf(second, m2);
    if (idx != 3) second = fmaxf(second, m3);
    gap = best - second;
}

// Issue 16 prefetch loads for (tile tb, half ph) into named regs pf0..pf15.
#define LOADN(n, tb, ph)                                                       \
    {                                                                          \
        int rr = (tb) + (n)*8 + hi3;                                           \
        if (rr >= B) rr = B - 1; /* clamp: dup read, never stored */           \
        pf##n = X4[(size_t)rr * 16 + (ph)*8 + f8];                             \
    }
#define ISSUE(tb, ph)                                                          \
    LOADN(0, tb, ph) LOADN(1, tb, ph) LOADN(2, tb, ph) LOADN(3, tb, ph)        \
    LOADN(4, tb, ph) LOADN(5, tb, ph) LOADN(6, tb, ph) LOADN(7, tb, ph)        \
    LOADN(8, tb, ph) LOADN(9, tb, ph) LOADN(10, tb, ph) LOADN(11, tb, ph)      \
    LOADN(12, tb, ph) LOADN(13, tb, ph) LOADN(14, tb, ph) LOADN(15, tb, ph)

// Commit pf0..pf15 into the wave's buffer (same addressing as r9 staging).
#define COMMN(n) *reinterpret_cast<float4*>(&buf[(n)*8 + hi3][f8 * 4]) = pf##n;
#define COMMIT()                                                               \
    COMMN(0) COMMN(1) COMMN(2) COMMN(3) COMMN(4) COMMN(5) COMMN(6) COMMN(7)    \
    COMMN(8) COMMN(9) COMMN(10) COMMN(11) COMMN(12) COMMN(13) COMMN(14)        \
    COMMN(15)

// r9's compute: per 4-d chunk, 2 lane b128 + 11 uniform W-quad b128 + 88 fma.
#define COMPUTE(ph)                                                            \
    {                                                                          \
        _Pragma("unroll 1") for (int kk = 0; kk < 8; ++kk) {                   \
            const float* wrow = &w_lds[((ph)*8 + kk) * 44];                    \
            float4 x0 = *reinterpret_cast<const float4*>(&buf[lane][kk * 4]);  \
            float4 x1 =                                                        \
                *reinterpret_cast<const float4*>(&buf[lane + 64][kk * 4]);     \
            _Pragma("unroll") for (int p = 0; p < NP; ++p) {                   \
                float4 wq = *reinterpret_cast<const float4*>(&wrow[p * 4]);    \
                float t0 = fmaf(x0.x, wq.x, acc0[p]);                          \
                t0 = fmaf(x0.y, wq.y, t0);                                     \
                t0 = fmaf(x0.z, wq.z, t0);                                     \
                acc0[p] = fmaf(x0.w, wq.w, t0);                                \
                float t1 = fmaf(x1.x, wq.x, acc1[p]);                          \
                t1 = fmaf(x1.y, wq.y, t1);                                     \
                t1 = fmaf(x1.z, wq.z, t1);                                     \
                acc1[p] = fmaf(x1.w, wq.w, t1);                                \
            }                                                                  \
        }                                                                      \
    }

__global__ __launch_bounds__(128) void decode(const float* __restrict__ X,
                                              float* __restrict__ out, int B) {
    __shared__ float xbuf[2][128][LROW];  // 36864 B, wave-private (r9 exact)
    __shared__ float w_lds[704];          // 2816 B; total 39680 -> 4 blk/CU

    const int tid = threadIdx.x;
    const int lane = tid & 63;
    const int wv = tid >> 6;
    float(*buf)[LROW] = xbuf[wv];

    for (int t = tid; t < 176; t += 128)
        reinterpret_cast<float4*>(w_lds)[t] =
            reinterpret_cast<const float4*>(g_W32)[t];
    __syncthreads();  // only block-wide sync

    const float4* X4 = reinterpret_cast<const float4*>(X);
    const int f8 = lane & 7;
    const int hi3 = lane >> 3;
    const int gwave = blockIdx.x * 2 + wv;
    const int nwaves = gridDim.x * 2;
    const int stride = nwaves * 128;
    const int base0 = gwave * 128;
    if (base0 >= B) return;

    float4 pf0, pf1, pf2, pf3, pf4, pf5, pf6, pf7;
    float4 pf8, pf9, pf10, pf11, pf12, pf13, pf14, pf15;

    // Prologue: stage (base0, half 0) -- the one cold stall.
    ISSUE(base0, 0)
    COMMIT()
    __builtin_amdgcn_wave_barrier();

    #pragma unroll 1
    for (int base = base0; base < B; base += stride) {
        int nb = base + stride;
        if (nb >= B) nb = base;  // clamped prefetch on last iter (discarded)

        float acc0[NP], acc1[NP];
        #pragma unroll
        for (int p = 0; p < NP; ++p) { acc0[p] = 0.0f; acc1[p] = 0.0f; }

        // --- issue half-1 loads, then compute half-0 (hides ~900cy latency)
        ISSUE(base, 1)
        __builtin_amdgcn_sched_barrier(0);  // pin loads above the compute
        COMPUTE(0)
        __builtin_amdgcn_wave_barrier();    // all buf reads done (in-order DS)
        COMMIT()                            // write-after-read, same buffer
        __builtin_amdgcn_wave_barrier();

        // --- issue next tile's half-0 loads, then compute half-1
        ISSUE(nb, 0)
        __builtin_amdgcn_sched_barrier(0);
        COMPUTE(1)

        // --- epilogue (VMEM stores; ds_writes below exact-wait only loads)
        int idx0, idx1; float gap0, gap1;
        argmax_gap(acc0, idx0, gap0);
        argmax_gap(acc1, idx1, gap1);

        unsigned long long m0 = __ballot(gap0 < TAU);
        unsigned long long m1 = __ballot(gap1 < TAU);
        if (lane == 0) {
            g_bits[(base >> 6) + 0] = m0;
            g_bits[(base >> 6) + 1] = m1;
        }

        int r0 = base + lane, r1 = base + 64 + lane;
        if (r0 < B) {
            float4 o;
            o.x = (idx0 == 0) ? 1.0f : 0.0f;
            o.y = (idx0 == 1) ? 1.0f : 0.0f;
            o.z = (idx0 == 2) ? 1.0f : 0.0f;
            o.w = (idx0 == 3) ? 1.0f : 0.0f;
            reinterpret_cast<float4*>(out)[r0] = o;
        }
        if (r1 < B) {
            float4 o;
            o.x = (idx1 == 0) ? 1.0f : 0.0f;
            o.y = (idx1 == 1) ? 1.0f : 0.0f;
            o.z = (idx1 == 2) ? 1.0f : 0.0f;
            o.w = (idx1 == 3) ? 1.0f : 0.0f;
            reinterpret_cast<float4*>(out)[r1] = o;
        }

        __builtin_amdgcn_wave_barrier();  // buf reads of half-1 done
        COMMIT()                          // next tile's half-0 into buffer
        __builtin_amdgcn_wave_barrier();
    }
}

__global__ __launch_bounds__(256) void repair(const float* __restrict__ X,
                                              float* __restrict__ out, int B) {
    __shared__ double w64[704];
    const int tid = threadIdx.x;
    for (int i = tid; i < 704; i += 256) w64[i] = g_W64[i];
    __syncthreads();

    const int nwords = (B + 63) >> 6;
    for (int t = blockIdx.x * blockDim.x + tid; t < nwords;
         t += gridDim.x * blockDim.x) {
        unsigned long long m = g_bits[t];
        while (m) {
            int b = __builtin_ctzll(m);
            m &= m - 1;
            int row = t * 64 + b;
            if (row >= B) continue;

            double s[NP];
            #pragma unroll
            for (int p = 0; p < NP; ++p) s[p] = 0.0;
            #pragma unroll 1
            for (int d = 0; d < 64; ++d) {
                double x = (double)X[(size_t)row * 64 + d];
                #pragma unroll
                for (int p = 0; p < NP; ++p)
                    s[p] = fma(x, w64[d * NP + p], s[p]);
            }

            double m0 = fmax(fmax(s[0], s[1]), fmax(s[2], s[3]));
            double m1 = fmax(fmax(fmax(s[4], s[5]), s[6]), fmax(s[7], s[8]));
            double m2 = s[9], m3 = s[10];
            int idx = 0; double best = m0;
            if (m1 > best) { best = m1; idx = 1; }
            if (m2 > best) { best = m2; idx = 2; }
            if (m3 > best) { best = m3; idx = 3; }

            float4 o;
            o.x = (idx == 0) ? 1.0f : 0.0f;
            o.y = (idx == 1) ? 1.0f : 0.0f;
            o.z = (idx == 2) ? 1.0f : 0.0f;
            o.w = (idx == 3) ? 1.0f : 0.0f;
            reinterpret_cast<float4*>(out)[row] = o;
        }
    }
}

extern "C" void kernel_launch(void* const* d_in, const int* in_sizes, int n_in,
                              void* d_out, int out_size, void* d_ws, size_t ws_size,
                              hipStream_t stream) {
    const float* X = (const float*)d_in[0];
    const float* A = (const float*)d_in[1];
    float* out = (float*)d_out;
    const int B = in_sizes[0] / 64;

    hipLaunchKernelGGL(prep, dim3(1), dim3(64), 0, stream, A);
    hipLaunchKernelGGL(decode, dim3(1024), dim3(128), 0, stream, X, out, B);
    hipLaunchKernelGGL(repair, dim3(128), dim3(256), 0, stream, X, out, B);
}

// Round 16
// 78.280 us; speedup vs baseline: 2.7290x; 1.0660x over previous
//
#include <hip/hip_runtime.h>

// FixedActionDecoder: sims = (X/||x||) @ (A/||a||cols); segment-max over
// ACTION_INDEX=[0,0,0,0,1,1,1,1,1,2,3]; argmax; one-hot.
// Row-norm of X is argmax-invariant -> skipped.
//
// r16 = r13 = r9 EXACT (measured best: 77.8 / 78.7us, reproduced).
// Champion structure:
//  - decode: half-row phases (8 lanes/row -> every staging request covers a
//    full 128B line), 128-row wave tiles, 2 rows/lane, stride-36 LDS rows
//    (PMC-verified 0 bank conflicts), W broadcast from LDS as d-major quads
//    (11 uniform ds_read_b128 per chunk), 4 blocks/CU = 8 waves/CU.
//  - prep: parallel (~2us). repair: separate kernel, W64 via LDS copy.
// Convicted deviations (never retry):
//  r5/r10 DMA global_load_lds (W s_load chains / 1 wave/SIMD + stores in
//  vmcnt queue); r6 reg-staging arrays (scratch spill, 250MB WRITE);
//  r7/r8 quarter-phases (128B-line splits, 28% over-fetch); r7 fused prep
//  (serial chain on every block); r11 fused repair (__noinline__ in hot
//  loop, decode 66->146us); r12 steal atomics (vmcnt(0) drain/tile);
//  r14 per-lane streaming (2.4x over-fetch); r15 same-iter reg prefetch
//  (vmcnt(0) at commit defeats it, +4.7us).
// Numerics: f32 pass + gap<TAU ballot -> f64 repair kernel
// (r1/r2-validated; absmax 0 in every passing round).

#define NP 11
#define TAU 1e-3f
#define LROW 36  // LDS row stride (dwords): 32 data + 4 pad (verified 0-conflict)

__device__ __align__(16) float g_W32[704];      // [(d>>2)*44 + p*4 + (d&3)]
__device__ double g_W64[704];                   // [d*11 + p]
__device__ unsigned long long g_bits[1 << 20];  // near-tie flags, 1 bit/row

// Parallel prep (~2us): thread d owns row d of A; column norms via LDS.
__global__ void prep(const float* __restrict__ A) {
    __shared__ double sq[64][NP + 1];  // +1 pad
    __shared__ double sc[NP];
    const int d = threadIdx.x;  // 0..63
    double a[NP];
    #pragma unroll
    for (int p = 0; p < NP; ++p) {
        a[p] = (double)A[d * NP + p];
        sq[d][p] = a[p] * a[p];
    }
    __syncthreads();
    if (d < NP) {
        double ss = 0.0;
        #pragma unroll
        for (int r = 0; r < 64; ++r) ss += sq[r][d];
        sc[d] = 1.0 / fmax(sqrt(ss), 1e-8);
    }
    __syncthreads();
    #pragma unroll
    for (int p = 0; p < NP; ++p) {
        double w = a[p] * sc[p];
        g_W64[d * NP + p] = w;
        g_W32[(d >> 2) * 44 + p * 4 + (d & 3)] = (float)w;  // d-major quad
    }
}

__device__ __forceinline__ void argmax_gap(const float* s, int& idx, float& gap) {
    // Segment max per ACTION_INDEX = [0,0,0,0, 1,1,1,1,1, 2, 3]
    float m0 = fmaxf(fmaxf(s[0], s[1]), fmaxf(s[2], s[3]));
    float m1 = fmaxf(fmaxf(fmaxf(s[4], s[5]), s[6]), fmaxf(s[7], s[8]));
    float m2 = s[9], m3 = s[10];
    idx = 0; float best = m0;
    if (m1 > best) { best = m1; idx = 1; }
    if (m2 > best) { best = m2; idx = 2; }
    if (m3 > best) { best = m3; idx = 3; }
    float second = -3.4e38f;
    if (idx != 0) second = fmaxf(second, m0);
    if (idx != 1) second = fmaxf(second, m1);
    if (idx != 2) second = fmaxf(second, m2);
    if (idx != 3) second = fmaxf(second, m3);
    gap = best - second;
}

__global__ __launch_bounds__(128) void decode(const float* __restrict__ X,
                                              float* __restrict__ out, int B) {
    __shared__ float xbuf[2][128][LROW];  // 36864 B, wave-private halves
    __shared__ float w_lds[704];          // 2816 B; total 39680 -> 4 blk/CU

    const int tid = threadIdx.x;
    const int lane = tid & 63;
    const int wv = tid >> 6;
    float(*buf)[LROW] = xbuf[wv];

    // Copy W into LDS: 176 float4s over 128 threads.
    for (int t = tid; t < 176; t += 128)
        reinterpret_cast<float4*>(w_lds)[t] =
            reinterpret_cast<const float4*>(g_W32)[t];
    __syncthreads();  // only block-wide sync; rest is wave-private

    const float4* X4 = reinterpret_cast<const float4*>(X);
    const int gwave = blockIdx.x * 2 + wv;
    const int nwaves = gridDim.x * 2;

    #pragma unroll 1
    for (int base = gwave * 128; base < B; base += nwaves * 128) {
        float acc0[NP], acc1[NP];
        #pragma unroll
        for (int p = 0; p < NP; ++p) { acc0[p] = 0.0f; acc1[p] = 0.0f; }

        #pragma unroll
        for (int st = 0; st < 2; ++st) {  // d half: st*32 .. st*32+31
            // Stage 128 rows x 32 floats; instr i covers 8 FULL 128B lines
            // (8 lanes/row x 16 B contiguous).
            #pragma unroll
            for (int i = 0; i < 16; ++i) {
                int fid = i * 64 + lane;  // 0..1023
                int row = fid >> 3;       // 0..127
                int f = fid & 7;          // 0..7
                int r = base + row;
                if (r >= B) r = B - 1;    // tail clamp (dup read, harmless)
                float4 v = X4[(size_t)r * 16 + st * 8 + f];
                *reinterpret_cast<float4*>(&buf[row][f * 4]) = v;
            }
            __builtin_amdgcn_wave_barrier();  // wave-private buf: fence only

            // Per 4-d chunk: 2 lane b128 (X rows) + 11 uniform b128 (W
            // quads) + 88 v_fma_f32. unroll 1: W never bulk-hoisted (r2).
            #pragma unroll 1
            for (int kk = 0; kk < 8; ++kk) {
                const float* wrow = &w_lds[(st * 8 + kk) * 44];
                float4 x0 = *reinterpret_cast<const float4*>(&buf[lane][kk * 4]);
                float4 x1 = *reinterpret_cast<const float4*>(&buf[lane + 64][kk * 4]);
                #pragma unroll
                for (int p = 0; p < NP; ++p) {
                    float4 wq = *reinterpret_cast<const float4*>(&wrow[p * 4]);
                    float t0 = fmaf(x0.x, wq.x, acc0[p]);
                    t0 = fmaf(x0.y, wq.y, t0);
                    t0 = fmaf(x0.z, wq.z, t0);
                    acc0[p] = fmaf(x0.w, wq.w, t0);
                    float t1 = fmaf(x1.x, wq.x, acc1[p]);
                    t1 = fmaf(x1.y, wq.y, t1);
                    t1 = fmaf(x1.z, wq.z, t1);
                    acc1[p] = fmaf(x1.w, wq.w, t1);
                }
            }
            __builtin_amdgcn_wave_barrier();
        }

        int idx0, idx1; float gap0, gap1;
        argmax_gap(acc0, idx0, gap0);
        argmax_gap(acc1, idx1, gap1);

        unsigned long long m0 = __ballot(gap0 < TAU);
        unsigned long long m1 = __ballot(gap1 < TAU);
        if (lane == 0) {
            g_bits[(base >> 6) + 0] = m0;
            g_bits[(base >> 6) + 1] = m1;
        }

        int r0 = base + lane, r1 = base + 64 + lane;
        if (r0 < B) {
            float4 o;
            o.x = (idx0 == 0) ? 1.0f : 0.0f;
            o.y = (idx0 == 1) ? 1.0f : 0.0f;
            o.z = (idx0 == 2) ? 1.0f : 0.0f;
            o.w = (idx0 == 3) ? 1.0f : 0.0f;
            reinterpret_cast<float4*>(out)[r0] = o;
        }
        if (r1 < B) {
            float4 o;
            o.x = (idx1 == 0) ? 1.0f : 0.0f;
            o.y = (idx1 == 1) ? 1.0f : 0.0f;
            o.z = (idx1 == 2) ? 1.0f : 0.0f;
            o.w = (idx1 == 3) ? 1.0f : 0.0f;
            reinterpret_cast<float4*>(out)[r1] = o;
        }
    }
}

__global__ __launch_bounds__(256) void repair(const float* __restrict__ X,
                                              float* __restrict__ out, int B) {
    __shared__ double w64[704];  // copy of g_W64
    const int tid = threadIdx.x;
    for (int i = tid; i < 704; i += 256) w64[i] = g_W64[i];
    __syncthreads();

    const int nwords = (B + 63) >> 6;
    for (int t = blockIdx.x * blockDim.x + tid; t < nwords;
         t += gridDim.x * blockDim.x) {
        unsigned long long m = g_bits[t];
        while (m) {
            int b = __builtin_ctzll(m);
            m &= m - 1;
            int row = t * 64 + b;
            if (row >= B) continue;

            double s[NP];
            #pragma unroll
            for (int p = 0; p < NP; ++p) s[p] = 0.0;
            #pragma unroll 1
            for (int d = 0; d < 64; ++d) {
                double x = (double)X[(size_t)row * 64 + d];
                #pragma unroll
                for (int p = 0; p < NP; ++p)
                    s[p] = fma(x, w64[d * NP + p], s[p]);
            }

            double m0 = fmax(fmax(s[0], s[1]), fmax(s[2], s[3]));
            double m1 = fmax(fmax(fmax(s[4], s[5]), s[6]), fmax(s[7], s[8]));
            double m2 = s[9], m3 = s[10];
            int idx = 0; double best = m0;
            if (m1 > best) { best = m1; idx = 1; }
            if (m2 > best) { best = m2; idx = 2; }
            if (m3 > best) { best = m3; idx = 3; }

            float4 o;
            o.x = (idx == 0) ? 1.0f : 0.0f;
            o.y = (idx == 1) ? 1.0f : 0.0f;
            o.z = (idx == 2) ? 1.0f : 0.0f;
            o.w = (idx == 3) ? 1.0f : 0.0f;
            reinterpret_cast<float4*>(out)[row] = o;
        }
    }
}

extern "C" void kernel_launch(void* const* d_in, const int* in_sizes, int n_in,
                              void* d_out, int out_size, void* d_ws, size_t ws_size,
                              hipStream_t stream) {
    const float* X = (const float*)d_in[0];
    const float* A = (const float*)d_in[1];
    float* out = (float*)d_out;
    const int B = in_sizes[0] / 64;

    hipLaunchKernelGGL(prep, dim3(1), dim3(64), 0, stream, A);
    hipLaunchKernelGGL(decode, dim3(1024), dim3(128), 0, stream, X, out, B);
    hipLaunchKernelGGL(repair, dim3(128), dim3(256), 0, stream, X, out, B);
}